// Round 15
// baseline (261.722 us; speedup 1.0000x reference)
//
#include <hip/hip_runtime.h>

#define Bq 128
#define Sq 512
#define Cq 37
#define Dq 768
#define VST 40

typedef __attribute__((ext_vector_type(2))) float f32x2;
typedef __attribute__((ext_vector_type(4))) float f32x4;
typedef __attribute__((ext_vector_type(8))) short bf16x8;

static __device__ __forceinline__ f32x2 pk_fma(f32x2 a, f32x2 b, f32x2 c) {
  f32x2 d; asm("v_pk_fma_f32 %0, %1, %2, %3" : "=v"(d) : "v"(a), "v"(b), "v"(c));
  return d;
}
static __device__ __forceinline__ f32x2 pk_add(f32x2 a, f32x2 b) {
  f32x2 d; asm("v_pk_add_f32 %0, %1, %2" : "=v"(d) : "v"(a), "v"(b));
  return d;
}
static __device__ __forceinline__ float bcast(float v, int p) {
  return __int_as_float(__builtin_amdgcn_ds_bpermute(p << 2, __float_as_int(v)));
}

#define REP18(X) X(0)X(1)X(2)X(3)X(4)X(5)X(6)X(7)X(8)X(9)X(10)X(11)X(12)X(13) \
  X(14)X(15)X(16)X(17)
#define REP37(X) X(0)X(1)X(2)X(3)X(4)X(5)X(6)X(7)X(8)X(9)X(10)X(11)X(12)X(13) \
  X(14)X(15)X(16)X(17)X(18)X(19)X(20)X(21)X(22)X(23)X(24)X(25)X(26)X(27)X(28) \
  X(29)X(30)X(31)X(32)X(33)X(34)X(35)X(36)

// Exchange issue: 1 ds_write_b32 + 10 ds_read_b128 (uniform base = broadcast)
// + 1 ds_read_b32 (em prefetch). 12 DS ops, in-order -> counted lgkmcnt works.
#define ISSUE(AW, VAL, BASE, GV, RAW, RADDR)                                   \
  asm volatile("ds_write_b32 %0, %1" :: "v"(AW), "v"(VAL));                    \
  asm volatile("ds_read_b128 %0, %1 offset:0"   : "=v"(GV[0]) : "v"(BASE));    \
  asm volatile("ds_read_b128 %0, %1 offset:16"  : "=v"(GV[1]) : "v"(BASE));    \
  asm volatile("ds_read_b128 %0, %1 offset:32"  : "=v"(GV[2]) : "v"(BASE));    \
  asm volatile("ds_read_b128 %0, %1 offset:48"  : "=v"(GV[3]) : "v"(BASE));    \
  asm volatile("ds_read_b128 %0, %1 offset:64"  : "=v"(GV[4]) : "v"(BASE));    \
  asm volatile("ds_read_b128 %0, %1 offset:80"  : "=v"(GV[5]) : "v"(BASE));    \
  asm volatile("ds_read_b128 %0, %1 offset:96"  : "=v"(GV[6]) : "v"(BASE));    \
  asm volatile("ds_read_b128 %0, %1 offset:112" : "=v"(GV[7]) : "v"(BASE));    \
  asm volatile("ds_read_b128 %0, %1 offset:128" : "=v"(GV[8]) : "v"(BASE));    \
  asm volatile("ds_read_b128 %0, %1 offset:144" : "=v"(GV[9]) : "v"(BASE));    \
  asm volatile("ds_read_b32 %0, %1" : "=v"(RAW) : "v"(RADDR));

#define WAIT12                                                                 \
  __builtin_amdgcn_sched_barrier(0);                                           \
  asm volatile("s_waitcnt lgkmcnt(12)");                                       \
  __builtin_amdgcn_sched_barrier(0);

// ---------------- Kernel 0: pre-split W into bf16 hi/lo B-fragments ----------------
__global__ __launch_bounds__(256) void prep_kernel(
    const float* __restrict__ W, unsigned short* __restrict__ Wbh,
    unsigned short* __restrict__ Wbl)
{
  int i = blockIdx.x * 256 + threadIdx.x;
  if (i >= 24 * 3 * 64 * 8) return;
  int ks = i / 1536, rem = i % 1536;
  int nt = rem / 512, rem2 = rem % 512;
  int lane = rem2 >> 3, j = rem2 & 7;
  int k = ks * 32 + (lane >> 4) * 8 + j;
  int c = nt * 16 + (lane & 15);
  float w = (c < Cq) ? W[(size_t)k * Cq + c] : 0.f;
  unsigned u = __float_as_uint(w);
  unsigned short h = (unsigned short)(u >> 16);
  float hr = __uint_as_float((unsigned)h << 16);
  float r = w - hr;
  Wbh[i] = h;
  Wbl[i] = (unsigned short)(__float_as_uint(r) >> 16);
}

// ---------------- Kernel 1: emissions via MFMA (R14, unchanged) ----------------
__global__ __launch_bounds__(256) void emis_kernel(
    const float* __restrict__ x, const unsigned short* __restrict__ Wbh,
    const unsigned short* __restrict__ Wbl, const float* __restrict__ bias,
    float* __restrict__ em)
{
  int tid = threadIdx.x, lane = tid & 63;
  int wv = tid >> 6;
  int tokBase = blockIdx.x * 64 + wv * 16;
  int row = lane & 15, kg = lane >> 4;
  const float* xr = x + (size_t)(tokBase + row) * Dq + kg * 8;
  const bf16x8* Bh = (const bf16x8*)Wbh;
  const bf16x8* Bl = (const bf16x8*)Wbl;
  f32x4 acc0 = {0.f, 0.f, 0.f, 0.f};
  f32x4 acc1 = {0.f, 0.f, 0.f, 0.f};
  f32x4 acc2 = {0.f, 0.f, 0.f, 0.f};

  float4 c0 = *(const float4*)(xr);
  float4 c1 = *(const float4*)(xr + 4);
  for (int ks = 0; ks < 24; ++ks) {
    float4 n0, n1;
    if (ks < 23) {
      n0 = *(const float4*)(xr + (ks + 1) * 32);
      n1 = *(const float4*)(xr + (ks + 1) * 32 + 4);
    }
    bf16x8 ah, al;
#define SPLIT(J, V) { unsigned u = __float_as_uint(V); \
    unsigned short h = (unsigned short)(u >> 16); \
    float hr = __uint_as_float((unsigned)h << 16); \
    float rr = (V) - hr; \
    ah[J] = (short)h; al[J] = (short)(__float_as_uint(rr) >> 16); }
    SPLIT(0, c0.x) SPLIT(1, c0.y) SPLIT(2, c0.z) SPLIT(3, c0.w)
    SPLIT(4, c1.x) SPLIT(5, c1.y) SPLIT(6, c1.z) SPLIT(7, c1.w)
#undef SPLIT
    int fi = (ks * 3) * 64 + lane;
    bf16x8 bh0 = Bh[fi], bh1 = Bh[fi + 64], bh2 = Bh[fi + 128];
    bf16x8 bl0 = Bl[fi], bl1 = Bl[fi + 64], bl2 = Bl[fi + 128];
    acc0 = __builtin_amdgcn_mfma_f32_16x16x32_bf16(al, bh0, acc0, 0, 0, 0);
    acc1 = __builtin_amdgcn_mfma_f32_16x16x32_bf16(al, bh1, acc1, 0, 0, 0);
    acc2 = __builtin_amdgcn_mfma_f32_16x16x32_bf16(al, bh2, acc2, 0, 0, 0);
    acc0 = __builtin_amdgcn_mfma_f32_16x16x32_bf16(ah, bl0, acc0, 0, 0, 0);
    acc1 = __builtin_amdgcn_mfma_f32_16x16x32_bf16(ah, bl1, acc1, 0, 0, 0);
    acc2 = __builtin_amdgcn_mfma_f32_16x16x32_bf16(ah, bl2, acc2, 0, 0, 0);
    acc0 = __builtin_amdgcn_mfma_f32_16x16x32_bf16(ah, bh0, acc0, 0, 0, 0);
    acc1 = __builtin_amdgcn_mfma_f32_16x16x32_bf16(ah, bh1, acc1, 0, 0, 0);
    acc2 = __builtin_amdgcn_mfma_f32_16x16x32_bf16(ah, bh2, acc2, 0, 0, 0);
    c0 = n0; c1 = n1;
  }
  int colc = lane & 15;
#pragma unroll
  for (int r = 0; r < 4; ++r) {
    size_t tok = (size_t)tokBase + kg * 4 + r;
    em[tok * Cq + colc]      = acc0[r] + bias[colc];
    em[tok * Cq + 16 + colc] = acc1[r] + bias[16 + colc];
    if (colc < 5)
      em[tok * Cq + 32 + colc] = acc2[r] + bias[32 + colc];
  }
}

// ---------------- Kernel 2: serial CRF — fwd+vit fused in ONE wave ----------------
// Counted lgkmcnt(12) software pipeline: vit's DS exchange in flight while
// fwd computes, and vice versa. Op order per chain identical to R14.
__global__ __launch_bounds__(256) void crf_serial_kernel(
    const float* __restrict__ em, const float* __restrict__ startv,
    const float* __restrict__ endv, const float* __restrict__ trans,
    const int* __restrict__ labels, const unsigned char* __restrict__ maskb,
    float* __restrict__ vhist, float* __restrict__ llp,
    int* __restrict__ lenp, int* __restrict__ lastp)
{
  __shared__ float semm[(Sq + 4) * Cq];
  __shared__ __align__(16) float sexchA[64];
  __shared__ __align__(16) float sexchB[64];
  __shared__ float s_score, s_logZ;
  int b = blockIdx.x;
  int tid = threadIdx.x, wid = tid >> 6, lane = tid & 63;
  int cl = lane < Cq ? lane : Cq - 1;

  int esz4 = (maskb[1] == 0) ? 1 : 0;
  int len = 0;
#pragma unroll
  for (int k = 0; k < 8; ++k) {
    size_t t = (size_t)lane + (size_t)k * 64;
    unsigned char mb = esz4 ? maskb[((size_t)b * Sq + t) * 4] : maskb[(size_t)b * Sq + t];
    len += (mb != 0);
  }
#pragma unroll
  for (int off = 32; off; off >>= 1) len += __shfl_xor(len, off);

  const float4* src4 = (const float4*)(em + (size_t)b * Sq * Cq);
  float4* dst4 = (float4*)semm;
  for (int i = tid; i < (Sq * Cq) / 4; i += 256) dst4[i] = src4[i];
  if (tid < 4 * Cq) semm[Sq * Cq + tid] = 0.f;
  __syncthreads();

  const float L2E = 1.4426950408889634f, LN2 = 0.6931471805599453f;

  if (wid == 0) {
    // ---- constants for both chains ----
    f32x2 E2[18], T2[18];
#pragma unroll
    for (int i = 0; i < 18; ++i) {
      E2[i][0] = exp2f(trans[(2 * i) * Cq + cl] * L2E);
      E2[i][1] = exp2f(trans[(2 * i + 1) * Cq + cl] * L2E);
      T2[i][0] = trans[(2 * i) * Cq + cl];
      T2[i][1] = trans[(2 * i + 1) * Cq + cl];
    }
    float E36 = exp2f(trans[36 * Cq + cl] * L2E);
    float T36 = trans[36 * Cq + cl];
    // ---- state init ----
    float a0 = (lane < Cq) ? (startv[cl] + semm[cl]) : -3.0e38f;
    float K0 = bcast(a0, 0);
    float ez = (lane < Cq) ? exp2f((a0 - K0) * L2E) : 0.f;
    int eacc = 0;
    float v = a0;
    if (lane < Cq) vhist[((size_t)b * Sq) * VST + cl] = v;
    float wA = exp2f(semm[1 * Cq + cl] * L2E), wB = exp2f(semm[2 * Cq + cl] * L2E);
    float wC = exp2f(semm[3 * Cq + cl] * L2E), wD = exp2f(semm[4 * Cq + cl] * L2E);
    float emA = semm[1 * Cq + cl], emB = semm[2 * Cq + cl];
    float emC = semm[3 * Cq + cl], emD = semm[4 * Cq + cl];

    unsigned baseA = (unsigned)(unsigned long long)(&sexchA[0]);
    unsigned baseB = (unsigned)(unsigned long long)(&sexchB[0]);
    unsigned aWA = baseA + (unsigned)lane * 4u;
    unsigned aWB = baseB + (unsigned)lane * 4u;
    unsigned sBse = (unsigned)(unsigned long long)(&semm[0]);
    f32x4 gvA[10], gvB[10];
    float rawA, rawB;

    { // preloop: issue fwd exchange for step 1 (raw idx 5; len>=16)
      unsigned rAddr = sBse + (unsigned)(5 * Cq + cl) * 4u;
      ISSUE(aWA, ez, baseA, gvA, rawA, rAddr)
    }
    for (int t = 1; t < len; ++t) {
      { // issue vit exchange for step t
        int rb = (t + 4 < len) ? t + 4 : len - 1;
        unsigned rAddr = sBse + (unsigned)(rb * Cq + cl) * 4u;
        ISSUE(aWB, v, baseB, gvB, rawB, rAddr)
      }
      WAIT12     // fwd's 12 DS ops done; vit's 12 still in flight
      { // ---- compute fwd step t ----
        int e0 = ((__float_as_int(gvA[0][0]) >> 23) & 255) - 127;
        float scale = __int_as_float((127 - e0) << 23);
        f32x2 sa = {0.f, 0.f}, sb2 = {0.f, 0.f};
#define FPK(i) { f32x2 g; \
        g[0] = gvA[(i) >> 1][((i) & 1) * 2]; \
        g[1] = gvA[(i) >> 1][((i) & 1) * 2 + 1]; \
        if ((i) & 1) sb2 = pk_fma(g, E2[i], sb2); else sa = pk_fma(g, E2[i], sa); }
        REP18(FPK)
#undef FPK
        float dot = ((sa[0] + sb2[0]) + (sa[1] + sb2[1])) + gvA[9][0] * E36;
        float wcur = wA; wA = wB; wB = wC; wC = wD;
        ez = dot * (wcur * scale);
        eacc += e0;
        wD = exp2f(rawA * L2E);
      }
      { // issue fwd exchange for step t+1 (last iter: dangling, harmless)
        int ra = (t + 5 < len) ? t + 5 : len - 1;
        unsigned rAddr = sBse + (unsigned)(ra * Cq + cl) * 4u;
        ISSUE(aWA, ez, baseA, gvA, rawA, rAddr)
      }
      WAIT12     // vit's 12 done; fwd's next 12 in flight
      { // ---- compute vit step t ----
        float m0 = -3.0e38f, m1 = -3.0e38f, m2 = -3.0e38f, m3 = -3.0e38f;
#define VPK(i) { f32x2 g; \
        g[0] = gvB[(i) >> 1][((i) & 1) * 2]; \
        g[1] = gvB[(i) >> 1][((i) & 1) * 2 + 1]; \
        f32x2 c = pk_add(g, T2[i]); \
        if (((i) & 3) == 0) m0 = fmaxf(fmaxf(m0, c[0]), c[1]); \
        else if (((i) & 3) == 1) m1 = fmaxf(fmaxf(m1, c[0]), c[1]); \
        else if (((i) & 3) == 2) m2 = fmaxf(fmaxf(m2, c[0]), c[1]); \
        else m3 = fmaxf(fmaxf(m3, c[0]), c[1]); }
        REP18(VPK)
#undef VPK
        float c36 = gvB[9][0] + T36;
        float best = fmaxf(fmaxf(fmaxf(m0, m1), fmaxf(m2, m3)), c36);
        float emc = emA; emA = emB; emB = emC; emC = emD;
        v = (lane < Cq) ? best + emc : -3.0e38f;
        if (lane < Cq) vhist[((size_t)b * Sq + t) * VST + cl] = v;
        emD = rawB;
      }
    }
    { // ---- fwd epilogue: logZ ----
      float xv = (lane < Cq) ? LN2 * (log2f(ez) + (float)eacc) + K0 + endv[cl] : -3.0e38f;
      float mm = xv;
#pragma unroll
      for (int off = 32; off; off >>= 1) mm = fmaxf(mm, __shfl_xor(mm, off));
      float es = exp2f((xv - mm) * L2E);
#pragma unroll
      for (int off = 32; off; off >>= 1) es += __shfl_xor(es, off);
      if (lane == 0) s_logZ = mm + log2f(es) * LN2;
    }
    { // ---- vit epilogue: argmax ----
      float xv = (lane < Cq) ? v + endv[cl] : -3.0e38f;
      int idx = (lane < Cq) ? lane : 1000;
#pragma unroll
      for (int off = 32; off; off >>= 1) {
        float xo = __shfl_xor(xv, off); int io = __shfl_xor(idx, off);
        if (xo > xv || (xo == xv && io < idx)) { xv = xo; idx = io; }
      }
      if (lane == 0) { lastp[b] = idx; lenp[b] = len; }
    }
  } else if (wid == 1) {
    // ---- gold path score ----
    const int* lab = labels + (size_t)b * Sq;
    float sc = 0.f;
#pragma unroll
    for (int k = 0; k < 8; ++k) {
      int t = 1 + lane + k * 64;
      if (t < len) {
        int lp = lab[t - 1], lt = lab[t];
        sc += trans[lp * Cq + lt] + semm[t * Cq + lt];
      }
    }
#pragma unroll
    for (int off = 32; off; off >>= 1) sc += __shfl_xor(sc, off);
    if (lane == 0) {
      int l0 = lab[0], lf = lab[len - 1];
      s_score = sc + startv[l0] + semm[l0] + endv[lf];
    }
  }
  __syncthreads();
  if (tid == 0) llp[b] = s_score - s_logZ;
}

// ---------------- Kernel 3: backpointers (parallel recompute) ----------------
__global__ __launch_bounds__(256) void crf_bp_kernel(
    const float* __restrict__ vhist, const float* __restrict__ trans,
    const int* __restrict__ lenp, unsigned char* __restrict__ bp)
{
  int b = blockIdx.x >> 2, chunk = blockIdx.x & 3;
  int wid = threadIdx.x >> 6, lane = threadIdx.x & 63;
  int cl = lane < Cq ? lane : Cq - 1;
  int len = lenp[b];
#define DECLT(i) float T##i = trans[(i) * Cq + cl];
  REP37(DECLT)
  int tend = 1 + (chunk + 1) * 128; if (tend > len) tend = len;
  int rl9 = lane < VST ? lane : VST - 1;
  for (int t = 1 + chunk * 128 + wid; t < tend; t += 4) {
    float vr = vhist[((size_t)b * Sq + (t - 1)) * VST + rl9];
#define BCASTB(i) float br##i = bcast(vr, (i));
    REP37(BCASTB)
    float best = -3.0e38f; int bi = 0;
#define BARG(i) { float cnd = br##i + T##i; if (cnd > best) { best = cnd; bi = (i); } }
    REP37(BARG)
    if (lane < Cq) bp[((size_t)b * VST + cl) * Sq + t] = (unsigned char)bi;
  }
}

// ---------------- Kernel 4: register-resident backtrack ----------------
__global__ __launch_bounds__(64) void crf_back_kernel(
    const unsigned char* __restrict__ bp, const int* __restrict__ lenp,
    const int* __restrict__ lastp, float* __restrict__ outp)
{
  int b = blockIdx.x, lane = threadIdx.x;
  int len = __builtin_amdgcn_readfirstlane(lenp[b]);
  int tag = __builtin_amdgcn_readfirstlane(lastp[b]);
  int row = lane < VST ? lane : VST - 1;
  const uint4* src = (const uint4*)(bp + ((size_t)b * VST + row) * Sq);
  unsigned r[128];
#pragma unroll
  for (int k = 0; k < 32; ++k) {
    uint4 q = src[k];
    r[4 * k] = q.x; r[4 * k + 1] = q.y; r[4 * k + 2] = q.z; r[4 * k + 3] = q.w;
  }
  unsigned vt[8];
#pragma unroll
  for (int j = 0; j < 8; ++j) vt[j] = 0u;
  vt[7] = (lane == 63) ? (unsigned)tag : vt[7];
#pragma unroll
  for (int t = 510; t >= 0; --t) {
    int word = __builtin_amdgcn_readlane((int)r[(t + 1) >> 2], tag);
    int nt = (word >> (((t + 1) & 3) * 8)) & 0xff;
    tag = (t + 1 < len) ? nt : tag;
    vt[t >> 6] = (lane == (t & 63)) ? (unsigned)tag : vt[t >> 6];
  }
#pragma unroll
  for (int j = 0; j < 8; ++j) {
    int t = j * 64 + lane;
    float o = (t < len) ? (float)(int)vt[j] : 36.0f;
    outp[(size_t)b * Sq + t] = o;
  }
}

// ---------------- Kernel 5: reduce ll partials ----------------
__global__ __launch_bounds__(64) void ll_reduce_kernel(
    const float* __restrict__ llp, float* __restrict__ outp)
{
  int lane = threadIdx.x;
  float s = llp[lane] + llp[lane + 64];
#pragma unroll
  for (int off = 32; off; off >>= 1) s += __shfl_xor(s, off);
  if (lane == 0) outp[0] = s;
}

extern "C" void kernel_launch(void* const* d_in, const int* in_sizes, int n_in,
                              void* d_out, int out_size, void* d_ws, size_t ws_size,
                              hipStream_t stream)
{
  const float* x      = (const float*)d_in[0];
  const float* W      = (const float*)d_in[1];
  const float* bias   = (const float*)d_in[2];
  const float* startv = (const float*)d_in[3];
  const float* endv   = (const float*)d_in[4];
  const float* trans  = (const float*)d_in[5];
  const int*   labels = (const int*)d_in[6];
  const unsigned char* maskb = (const unsigned char*)d_in[7];
  float* out = (float*)d_out;

  char* ws = (char*)d_ws;
  float* em            = (float*)(ws);
  float* vhist         = (float*)(ws + 9699328);
  unsigned char* bpbuf = (unsigned char*)(ws + 20185088);
  float* llp           = (float*)(ws + 22806528);
  int*   lenp          = (int*)(ws + 22807552);
  int*   lastp         = (int*)(ws + 22808064);
  unsigned short* Wbh  = (unsigned short*)(ws + 22808576);
  unsigned short* Wbl  = (unsigned short*)(ws + 22882304);

  prep_kernel<<<144, 256, 0, stream>>>(W, Wbh, Wbl);
  emis_kernel<<<1024, 256, 0, stream>>>(x, Wbh, Wbl, bias, em);
  crf_serial_kernel<<<128, 256, 0, stream>>>(em, startv, endv, trans, labels, maskb,
                                             vhist, llp, lenp, lastp);
  crf_bp_kernel<<<512, 256, 0, stream>>>(vhist, trans, lenp, bpbuf);
  crf_back_kernel<<<128, 64, 0, stream>>>(bpbuf, lenp, lastp, out + 1);
  ll_reduce_kernel<<<1, 64, 0, stream>>>(llp, out);
}

// Round 16
// 203.587 us; speedup vs baseline: 1.2856x; 1.2856x over previous
//
#include <hip/hip_runtime.h>

#define Bq 128
#define Sq 512
#define Cq 37
#define Dq 768
#define VST 40

typedef __attribute__((ext_vector_type(2))) float f32x2;
typedef __attribute__((ext_vector_type(4))) float f32x4;
typedef __attribute__((ext_vector_type(8))) short bf16x8;

static __device__ __forceinline__ f32x2 pk_fma(f32x2 a, f32x2 b, f32x2 c) {
  f32x2 d; asm("v_pk_fma_f32 %0, %1, %2, %3" : "=v"(d) : "v"(a), "v"(b), "v"(c));
  return d;
}
static __device__ __forceinline__ f32x2 pk_add(f32x2 a, f32x2 b) {
  f32x2 d; asm("v_pk_add_f32 %0, %1, %2" : "=v"(d) : "v"(a), "v"(b));
  return d;
}
static __device__ __forceinline__ float bcast(float v, int p) {
  return __int_as_float(__builtin_amdgcn_ds_bpermute(p << 2, __float_as_int(v)));
}

#define REP18(X) X(0)X(1)X(2)X(3)X(4)X(5)X(6)X(7)X(8)X(9)X(10)X(11)X(12)X(13) \
  X(14)X(15)X(16)X(17)
#define REP37(X) X(0)X(1)X(2)X(3)X(4)X(5)X(6)X(7)X(8)X(9)X(10)X(11)X(12)X(13) \
  X(14)X(15)X(16)X(17)X(18)X(19)X(20)X(21)X(22)X(23)X(24)X(25)X(26)X(27)X(28) \
  X(29)X(30)X(31)X(32)X(33)X(34)X(35)X(36)

// ---------------- Kernel 0: pre-split W into bf16 hi/lo B-fragments ----------------
__global__ __launch_bounds__(256) void prep_kernel(
    const float* __restrict__ W, unsigned short* __restrict__ Wbh,
    unsigned short* __restrict__ Wbl)
{
  int i = blockIdx.x * 256 + threadIdx.x;
  if (i >= 24 * 3 * 64 * 8) return;
  int ks = i / 1536, rem = i % 1536;
  int nt = rem / 512, rem2 = rem % 512;
  int lane = rem2 >> 3, j = rem2 & 7;
  int k = ks * 32 + (lane >> 4) * 8 + j;
  int c = nt * 16 + (lane & 15);
  float w = (c < Cq) ? W[(size_t)k * Cq + c] : 0.f;
  unsigned u = __float_as_uint(w);
  unsigned short h = (unsigned short)(u >> 16);
  float hr = __uint_as_float((unsigned)h << 16);
  float r = w - hr;
  Wbh[i] = h;
  Wbl[i] = (unsigned short)(__float_as_uint(r) >> 16);
}

// ---------------- Kernel 1: emissions via MFMA (R14, unchanged) ----------------
__global__ __launch_bounds__(256) void emis_kernel(
    const float* __restrict__ x, const unsigned short* __restrict__ Wbh,
    const unsigned short* __restrict__ Wbl, const float* __restrict__ bias,
    float* __restrict__ em)
{
  int tid = threadIdx.x, lane = tid & 63;
  int wv = tid >> 6;
  int tokBase = blockIdx.x * 64 + wv * 16;
  int row = lane & 15, kg = lane >> 4;
  const float* xr = x + (size_t)(tokBase + row) * Dq + kg * 8;
  const bf16x8* Bh = (const bf16x8*)Wbh;
  const bf16x8* Bl = (const bf16x8*)Wbl;
  f32x4 acc0 = {0.f, 0.f, 0.f, 0.f};
  f32x4 acc1 = {0.f, 0.f, 0.f, 0.f};
  f32x4 acc2 = {0.f, 0.f, 0.f, 0.f};

  float4 c0 = *(const float4*)(xr);
  float4 c1 = *(const float4*)(xr + 4);
  for (int ks = 0; ks < 24; ++ks) {
    float4 n0, n1;
    if (ks < 23) {
      n0 = *(const float4*)(xr + (ks + 1) * 32);
      n1 = *(const float4*)(xr + (ks + 1) * 32 + 4);
    }
    bf16x8 ah, al;
#define SPLIT(J, V) { unsigned u = __float_as_uint(V); \
    unsigned short h = (unsigned short)(u >> 16); \
    float hr = __uint_as_float((unsigned)h << 16); \
    float rr = (V) - hr; \
    ah[J] = (short)h; al[J] = (short)(__float_as_uint(rr) >> 16); }
    SPLIT(0, c0.x) SPLIT(1, c0.y) SPLIT(2, c0.z) SPLIT(3, c0.w)
    SPLIT(4, c1.x) SPLIT(5, c1.y) SPLIT(6, c1.z) SPLIT(7, c1.w)
#undef SPLIT
    int fi = (ks * 3) * 64 + lane;
    bf16x8 bh0 = Bh[fi], bh1 = Bh[fi + 64], bh2 = Bh[fi + 128];
    bf16x8 bl0 = Bl[fi], bl1 = Bl[fi + 64], bl2 = Bl[fi + 128];
    acc0 = __builtin_amdgcn_mfma_f32_16x16x32_bf16(al, bh0, acc0, 0, 0, 0);
    acc1 = __builtin_amdgcn_mfma_f32_16x16x32_bf16(al, bh1, acc1, 0, 0, 0);
    acc2 = __builtin_amdgcn_mfma_f32_16x16x32_bf16(al, bh2, acc2, 0, 0, 0);
    acc0 = __builtin_amdgcn_mfma_f32_16x16x32_bf16(ah, bl0, acc0, 0, 0, 0);
    acc1 = __builtin_amdgcn_mfma_f32_16x16x32_bf16(ah, bl1, acc1, 0, 0, 0);
    acc2 = __builtin_amdgcn_mfma_f32_16x16x32_bf16(ah, bl2, acc2, 0, 0, 0);
    acc0 = __builtin_amdgcn_mfma_f32_16x16x32_bf16(ah, bh0, acc0, 0, 0, 0);
    acc1 = __builtin_amdgcn_mfma_f32_16x16x32_bf16(ah, bh1, acc1, 0, 0, 0);
    acc2 = __builtin_amdgcn_mfma_f32_16x16x32_bf16(ah, bh2, acc2, 0, 0, 0);
    c0 = n0; c1 = n1;
  }
  int colc = lane & 15;
#pragma unroll
  for (int r = 0; r < 4; ++r) {
    size_t tok = (size_t)tokBase + kg * 4 + r;
    em[tok * Cq + colc]      = acc0[r] + bias[colc];
    em[tok * Cq + 16 + colc] = acc1[r] + bias[16 + colc];
    if (colc < 5)
      em[tok * Cq + 32 + colc] = acc2[r] + bias[32 + colc];
  }
}

// ---------------- Kernel 2: bidirectional CRF — 4 half-length chains ----------------
// wave0: alpha fwd 1..m   wave1: beta bwd len-2..m (row-dot)
// wave2: vit   fwd 1..m   wave3: vit-bwd u len-2..m   wave4: gold score
// merge: logZ = LSE(alpha_m+beta_m); mid tag c* = argmax(v_m+u_m).
// vhist slots 0..m hold v, slots m+1..len-1 hold u (disjoint).
__global__ __launch_bounds__(320) void crf_serial_kernel(
    const float* __restrict__ em, const float* __restrict__ startv,
    const float* __restrict__ endv, const float* __restrict__ trans,
    const int* __restrict__ labels, const unsigned char* __restrict__ maskb,
    float* __restrict__ vhist, float* __restrict__ llp,
    int* __restrict__ lenp, int* __restrict__ lastp, int* __restrict__ midp)
{
  __shared__ float semm[(Sq + 4) * Cq];
  __shared__ __align__(16) float sxA[64];
  __shared__ __align__(16) float sxB[64];
  __shared__ __align__(16) float sxC[64];
  __shared__ __align__(16) float sxD[64];
  __shared__ float mrgA[64], mrgB[64], mrgV[64], mrgU[64];
  __shared__ float s_score;
  int b = blockIdx.x;
  int tid = threadIdx.x, wid = tid >> 6, lane = tid & 63;
  int cl = lane < Cq ? lane : Cq - 1;

  int esz4 = (maskb[1] == 0) ? 1 : 0;
  int len = 0;
#pragma unroll
  for (int k = 0; k < 8; ++k) {
    size_t t = (size_t)lane + (size_t)k * 64;
    unsigned char mb = esz4 ? maskb[((size_t)b * Sq + t) * 4] : maskb[(size_t)b * Sq + t];
    len += (mb != 0);
  }
#pragma unroll
  for (int off = 32; off; off >>= 1) len += __shfl_xor(len, off);
  int m = len >> 1;                         // len >= 16 -> m >= 8

  const float4* src4 = (const float4*)(em + (size_t)b * Sq * Cq);
  float4* dst4 = (float4*)semm;
  for (int i = tid; i < (Sq * Cq) / 4; i += 320) dst4[i] = src4[i];
  if (tid < 4 * Cq) semm[Sq * Cq + tid] = 0.f;
  __syncthreads();

  const float L2E = 1.4426950408889634f, LN2 = 0.6931471805599453f;

  if (wid == 0) {
    // ---- alpha forward, exp domain, t = 1..m ----
    f32x2 E2[18];
#pragma unroll
    for (int i = 0; i < 18; ++i) {
      E2[i][0] = exp2f(trans[(2 * i) * Cq + cl] * L2E);
      E2[i][1] = exp2f(trans[(2 * i + 1) * Cq + cl] * L2E);
    }
    float E36 = exp2f(trans[36 * Cq + cl] * L2E);
    const float4* se4 = (const float4*)sxA;
    float a0 = (lane < Cq) ? (startv[cl] + semm[cl]) : -3.0e38f;
    float K0 = bcast(a0, 0);
    float ez = (lane < Cq) ? exp2f((a0 - K0) * L2E) : 0.f;
    int eacc = 0;
    float wA = exp2f(semm[1 * Cq + cl] * L2E), wB = exp2f(semm[2 * Cq + cl] * L2E);
    float wC = exp2f(semm[3 * Cq + cl] * L2E), wD = exp2f(semm[4 * Cq + cl] * L2E);
    for (int t = 1; t <= m; ++t) {
      sxA[lane] = ez;
      int tn = (t + 4 <= m) ? t + 4 : m;
      float raw = semm[tn * Cq + cl];
      float4 gv[10];
#pragma unroll
      for (int q = 0; q < 10; ++q) gv[q] = se4[q];
      int e0 = ((__float_as_int(gv[0].x) >> 23) & 255) - 127;
      float scale = __int_as_float((127 - e0) << 23);
      f32x2 sa = {0.f, 0.f}, sb2 = {0.f, 0.f};
#define FPK(i) { f32x2 g; \
      g[0] = ((i) & 1) ? gv[(i) >> 1].z : gv[(i) >> 1].x; \
      g[1] = ((i) & 1) ? gv[(i) >> 1].w : gv[(i) >> 1].y; \
      if ((i) & 1) sb2 = pk_fma(g, E2[i], sb2); else sa = pk_fma(g, E2[i], sa); }
      REP18(FPK)
#undef FPK
      float dot = ((sa[0] + sb2[0]) + (sa[1] + sb2[1])) + gv[9].x * E36;
      float wcur = wA; wA = wB; wB = wC; wC = wD;
      ez = dot * (wcur * scale);
      eacc += e0;
      wD = exp2f(raw * L2E);
    }
    mrgA[lane] = (lane < Cq) ? LN2 * (log2f(ez) + (float)eacc) + K0 : -3.0e38f;
  } else if (wid == 1) {
    // ---- beta backward, exp domain, t = len-2..m (row-dot) ----
    f32x2 E2[18];
#pragma unroll
    for (int i = 0; i < 18; ++i) {
      E2[i][0] = exp2f(trans[cl * Cq + 2 * i] * L2E);
      E2[i][1] = exp2f(trans[cl * Cq + 2 * i + 1] * L2E);
    }
    float E36 = exp2f(trans[cl * Cq + 36] * L2E);
    const float4* se4 = (const float4*)sxB;
    float b0v = (lane < Cq) ? endv[cl] : -3.0e38f;
    float KB = bcast(b0v, 0);
    float bz = (lane < Cq) ? exp2f((b0v - KB) * L2E) : 0.f;
    int eacc = 0;
    float wA = exp2f(semm[(len - 1) * Cq + cl] * L2E);
    float wB = exp2f(semm[(len - 2) * Cq + cl] * L2E);
    float wC = exp2f(semm[(len - 3) * Cq + cl] * L2E);
    float wD = exp2f(semm[(len - 4) * Cq + cl] * L2E);
    for (int t = len - 2; t >= m; --t) {
      float wcur = wA; wA = wB; wB = wC; wC = wD;
      float s = bz * wcur;                  // w[t+1] * beta[t+1], lane-local
      sxB[lane] = s;
      int tn = (t - 3 > 0) ? t - 3 : 0;
      float raw = semm[tn * Cq + cl];
      float4 gv[10];
#pragma unroll
      for (int q = 0; q < 10; ++q) gv[q] = se4[q];
      int e0 = ((__float_as_int(gv[0].x) >> 23) & 255) - 127;
      float scale = __int_as_float((127 - e0) << 23);
      f32x2 sa = {0.f, 0.f}, sb2 = {0.f, 0.f};
#define FPK(i) { f32x2 g; \
      g[0] = ((i) & 1) ? gv[(i) >> 1].z : gv[(i) >> 1].x; \
      g[1] = ((i) & 1) ? gv[(i) >> 1].w : gv[(i) >> 1].y; \
      if ((i) & 1) sb2 = pk_fma(g, E2[i], sb2); else sa = pk_fma(g, E2[i], sa); }
      REP18(FPK)
#undef FPK
      float dot = ((sa[0] + sb2[0]) + (sa[1] + sb2[1])) + gv[9].x * E36;
      bz = dot * scale;
      eacc += e0;
      wD = exp2f(raw * L2E);
    }
    mrgB[lane] = (lane < Cq) ? LN2 * (log2f(bz) + (float)eacc) + KB : -3.0e38f;
  } else if (wid == 2) {
    // ---- viterbi forward, t = 1..m ----
    f32x2 T2[18];
#pragma unroll
    for (int i = 0; i < 18; ++i) {
      T2[i][0] = trans[(2 * i) * Cq + cl];
      T2[i][1] = trans[(2 * i + 1) * Cq + cl];
    }
    float T36 = trans[36 * Cq + cl];
    const float4* sv4 = (const float4*)sxC;
    float v = (lane < Cq) ? (startv[cl] + semm[cl]) : -3.0e38f;
    if (lane < Cq) vhist[((size_t)b * Sq) * VST + cl] = v;
    float emA = semm[1 * Cq + cl], emB = semm[2 * Cq + cl];
    float emC = semm[3 * Cq + cl], emD = semm[4 * Cq + cl];
    for (int t = 1; t <= m; ++t) {
      sxC[lane] = v;
      int tn = (t + 4 <= m) ? t + 4 : m;
      float raw = semm[tn * Cq + cl];
      float4 gv[10];
#pragma unroll
      for (int q = 0; q < 10; ++q) gv[q] = sv4[q];
      float m0 = -3.0e38f, m1 = -3.0e38f, m2 = -3.0e38f, m3 = -3.0e38f;
#define VPK(i) { f32x2 g; \
      g[0] = ((i) & 1) ? gv[(i) >> 1].z : gv[(i) >> 1].x; \
      g[1] = ((i) & 1) ? gv[(i) >> 1].w : gv[(i) >> 1].y; \
      f32x2 c = pk_add(g, T2[i]); \
      if (((i) & 3) == 0) m0 = fmaxf(fmaxf(m0, c[0]), c[1]); \
      else if (((i) & 3) == 1) m1 = fmaxf(fmaxf(m1, c[0]), c[1]); \
      else if (((i) & 3) == 2) m2 = fmaxf(fmaxf(m2, c[0]), c[1]); \
      else m3 = fmaxf(fmaxf(m3, c[0]), c[1]); }
      REP18(VPK)
#undef VPK
      float c36 = gv[9].x + T36;
      float best = fmaxf(fmaxf(fmaxf(m0, m1), fmaxf(m2, m3)), c36);
      float emc = emA; emA = emB; emB = emC; emC = emD;
      v = (lane < Cq) ? best + emc : -3.0e38f;
      if (lane < Cq) vhist[((size_t)b * Sq + t) * VST + cl] = v;
      emD = raw;
    }
    mrgV[lane] = v;
  } else if (wid == 3) {
    // ---- viterbi backward u, t = len-2..m ----
    f32x2 T2[18];
#pragma unroll
    for (int i = 0; i < 18; ++i) {
      T2[i][0] = trans[cl * Cq + 2 * i];
      T2[i][1] = trans[cl * Cq + 2 * i + 1];
    }
    float T36 = trans[cl * Cq + 36];
    const float4* sv4 = (const float4*)sxD;
    float u = (lane < Cq) ? endv[cl] : -3.0e38f;
    if (lane < Cq) vhist[((size_t)b * Sq + (len - 1)) * VST + cl] = u;
    float emA = semm[(len - 1) * Cq + cl], emB = semm[(len - 2) * Cq + cl];
    float emC = semm[(len - 3) * Cq + cl], emD = semm[(len - 4) * Cq + cl];
    for (int t = len - 2; t >= m; --t) {
      float emc = emA; emA = emB; emB = emC; emC = emD;
      float s = u + emc;                    // u[t+1] + em[t+1], lane-local
      sxD[lane] = s;
      int tn = (t - 3 > 0) ? t - 3 : 0;
      float raw = semm[tn * Cq + cl];
      float4 gv[10];
#pragma unroll
      for (int q = 0; q < 10; ++q) gv[q] = sv4[q];
      float m0 = -3.0e38f, m1 = -3.0e38f, m2 = -3.0e38f, m3 = -3.0e38f;
#define VPK(i) { f32x2 g; \
      g[0] = ((i) & 1) ? gv[(i) >> 1].z : gv[(i) >> 1].x; \
      g[1] = ((i) & 1) ? gv[(i) >> 1].w : gv[(i) >> 1].y; \
      f32x2 c = pk_add(g, T2[i]); \
      if (((i) & 3) == 0) m0 = fmaxf(fmaxf(m0, c[0]), c[1]); \
      else if (((i) & 3) == 1) m1 = fmaxf(fmaxf(m1, c[0]), c[1]); \
      else if (((i) & 3) == 2) m2 = fmaxf(fmaxf(m2, c[0]), c[1]); \
      else m3 = fmaxf(fmaxf(m3, c[0]), c[1]); }
      REP18(VPK)
#undef VPK
      float c36 = gv[9].x + T36;
      float best = fmaxf(fmaxf(fmaxf(m0, m1), fmaxf(m2, m3)), c36);
      u = (lane < Cq) ? best : -3.0e38f;
      if (lane < Cq && t > m) vhist[((size_t)b * Sq + t) * VST + cl] = u;
      emD = raw;
    }
    mrgU[lane] = u;
  } else {
    // ---- gold path score ----
    const int* lab = labels + (size_t)b * Sq;
    float sc = 0.f;
#pragma unroll
    for (int k = 0; k < 8; ++k) {
      int t = 1 + lane + k * 64;
      if (t < len) {
        int lp = lab[t - 1], lt = lab[t];
        sc += trans[lp * Cq + lt] + semm[t * Cq + lt];
      }
    }
#pragma unroll
    for (int off = 32; off; off >>= 1) sc += __shfl_xor(sc, off);
    if (lane == 0) {
      int l0 = lab[0], lf = lab[len - 1];
      s_score = sc + startv[l0] + semm[l0] + endv[lf];
    }
  }
  __syncthreads();
  if (wid == 0) {
    // ---- merge: logZ + mid tag ----
    float xv = (lane < Cq) ? mrgA[lane] + mrgB[lane] : -3.0e38f;
    float mm = xv;
#pragma unroll
    for (int off = 32; off; off >>= 1) mm = fmaxf(mm, __shfl_xor(mm, off));
    float es = exp2f((xv - mm) * L2E);
#pragma unroll
    for (int off = 32; off; off >>= 1) es += __shfl_xor(es, off);
    float logZ = mm + log2f(es) * LN2;
    float pv = (lane < Cq) ? mrgV[lane] + mrgU[lane] : -3.0e38f;
    int idx = (lane < Cq) ? lane : 1000;
#pragma unroll
    for (int off = 32; off; off >>= 1) {
      float po = __shfl_xor(pv, off); int io = __shfl_xor(idx, off);
      if (po > pv || (po == pv && io < idx)) { pv = po; idx = io; }
    }
    if (lane == 0) {
      llp[b] = s_score - logZ;
      lastp[b] = idx; lenp[b] = len; midp[b] = m;
    }
  }
}

// ---------------- Kernel 3: bp (t<=m, from v) and fp (slots m+1..len-1, from u) ----
__global__ __launch_bounds__(256) void crf_bp_kernel(
    const float* __restrict__ vhist, const float* __restrict__ em,
    const float* __restrict__ trans, const int* __restrict__ lenp,
    const int* __restrict__ midp, unsigned char* __restrict__ bp)
{
  int role = blockIdx.x >> 9;
  int bid = blockIdx.x & 511;
  int b = bid >> 2, chunk = bid & 3;
  int wid = threadIdx.x >> 6, lane = threadIdx.x & 63;
  int cl = lane < Cq ? lane : Cq - 1;
  int len = lenp[b], m = midp[b];
  int rl9 = lane < VST ? lane : VST - 1;
  if (role == 0) {
    // backpointers: bp[t][c] = argmax_p(v[t-1][p] + T[p][c]), t = 1..m
#define DECLT(i) float T##i = trans[(i) * Cq + cl];
    REP37(DECLT)
#undef DECLT
    int tend = 1 + (chunk + 1) * 128; if (tend > m + 1) tend = m + 1;
    for (int t = 1 + chunk * 128 + wid; t < tend; t += 4) {
      float vr = vhist[((size_t)b * Sq + (t - 1)) * VST + rl9];
#define BCASTB(i) float br##i = bcast(vr, (i));
      REP37(BCASTB)
#undef BCASTB
      float best = -3.0e38f; int bi = 0;
#define BARG(i) { float cnd = br##i + T##i; if (cnd > best) { best = cnd; bi = (i); } }
      REP37(BARG)
#undef BARG
      if (lane < Cq) bp[((size_t)b * VST + cl) * Sq + t] = (unsigned char)bi;
    }
  } else {
    // forward-pointers: slot s (= t+1): fp[c] = argmax_n(T[c][n] + em[s][n] + u[s][n])
#define DECLR(i) float R##i = trans[cl * Cq + (i)];
    REP37(DECLR)
#undef DECLR
    int er = lane < Cq ? lane : 0;
    int s0 = m + 1 + chunk * 128 + wid;
    int send = m + 1 + (chunk + 1) * 128; if (send > len) send = len;
    for (int s = s0; s < send; s += 4) {
      float uv = vhist[((size_t)b * Sq + s) * VST + rl9];
      float ev = em[((size_t)b * Sq + s) * Cq + er];
      float sv = uv + ev;
#define BCASTB(i) float br##i = bcast(sv, (i));
      REP37(BCASTB)
#undef BCASTB
      float best = -3.0e38f; int bi = 0;
#define BARG(i) { float cnd = br##i + R##i; if (cnd > best) { best = cnd; bi = (i); } }
      REP37(BARG)
#undef BARG
      if (lane < Cq) bp[((size_t)b * VST + cl) * Sq + s] = (unsigned char)bi;
    }
  }
}

// ---------------- Kernel 4: backtrack both directions from mid tag ----------------
__global__ __launch_bounds__(64) void crf_back_kernel(
    const unsigned char* __restrict__ bp, const int* __restrict__ lenp,
    const int* __restrict__ lastp, const int* __restrict__ midp,
    float* __restrict__ outp)
{
  int b = blockIdx.x, lane = threadIdx.x;
  int len = __builtin_amdgcn_readfirstlane(lenp[b]);
  int m = __builtin_amdgcn_readfirstlane(midp[b]);
  int cstar = __builtin_amdgcn_readfirstlane(lastp[b]);
  int row = lane < VST ? lane : VST - 1;
  const uint4* src = (const uint4*)(bp + ((size_t)b * VST + row) * Sq);
  unsigned r[128];
#pragma unroll
  for (int k = 0; k < 32; ++k) {
    uint4 q = src[k];
    r[4 * k] = q.x; r[4 * k + 1] = q.y; r[4 * k + 2] = q.z; r[4 * k + 3] = q.w;
  }
  unsigned vt[8];
#pragma unroll
  for (int j = 0; j < 8; ++j) vt[j] = 0u;
  // seed mid tag at slot m (runtime m -> per-j select)
#pragma unroll
  for (int j = 0; j < 8; ++j)
    vt[j] = (lane == (m & 63) && (m >> 6) == j) ? (unsigned)cstar : vt[j];
  // forward walk: t = m+1..len-1, tag_t = fp(slot t)[tag_{t-1}]
  {
    int tag = cstar;
#pragma unroll
    for (int t = 1; t <= 510; ++t) {
      int word = __builtin_amdgcn_readlane((int)r[t >> 2], tag);
      int nt = (word >> ((t & 3) * 8)) & 0xff;
      bool live = (t > m) && (t < len);
      tag = live ? nt : tag;
      vt[t >> 6] = (lane == (t & 63) && live) ? (unsigned)tag : vt[t >> 6];
    }
  }
  // backward walk: t = m-1..0, tag_t = bp(slot t+1)[tag_{t+1}]
  {
    int tag = cstar;
#pragma unroll
    for (int t = 510; t >= 0; --t) {
      int word = __builtin_amdgcn_readlane((int)r[(t + 1) >> 2], tag);
      int nt = (word >> (((t + 1) & 3) * 8)) & 0xff;
      bool live = (t + 1 <= m);
      tag = live ? nt : tag;
      vt[t >> 6] = (lane == (t & 63) && live) ? (unsigned)tag : vt[t >> 6];
    }
  }
#pragma unroll
  for (int j = 0; j < 8; ++j) {
    int t = j * 64 + lane;
    float o = (t < len) ? (float)(int)vt[j] : 36.0f;
    outp[(size_t)b * Sq + t] = o;
  }
}

// ---------------- Kernel 5: reduce ll partials ----------------
__global__ __launch_bounds__(64) void ll_reduce_kernel(
    const float* __restrict__ llp, float* __restrict__ outp)
{
  int lane = threadIdx.x;
  float s = llp[lane] + llp[lane + 64];
#pragma unroll
  for (int off = 32; off; off >>= 1) s += __shfl_xor(s, off);
  if (lane == 0) outp[0] = s;
}

extern "C" void kernel_launch(void* const* d_in, const int* in_sizes, int n_in,
                              void* d_out, int out_size, void* d_ws, size_t ws_size,
                              hipStream_t stream)
{
  const float* x      = (const float*)d_in[0];
  const float* W      = (const float*)d_in[1];
  const float* bias   = (const float*)d_in[2];
  const float* startv = (const float*)d_in[3];
  const float* endv   = (const float*)d_in[4];
  const float* trans  = (const float*)d_in[5];
  const int*   labels = (const int*)d_in[6];
  const unsigned char* maskb = (const unsigned char*)d_in[7];
  float* out = (float*)d_out;

  char* ws = (char*)d_ws;
  float* em            = (float*)(ws);
  float* vhist         = (float*)(ws + 9699328);
  unsigned char* bpbuf = (unsigned char*)(ws + 20185088);
  float* llp           = (float*)(ws + 22806528);
  int*   lenp          = (int*)(ws + 22807552);
  int*   lastp         = (int*)(ws + 22808064);
  int*   midp          = (int*)(ws + 22809088);
  unsigned short* Wbh  = (unsigned short*)(ws + 22809600);
  unsigned short* Wbl  = (unsigned short*)(ws + 22883328);

  prep_kernel<<<144, 256, 0, stream>>>(W, Wbh, Wbl);
  emis_kernel<<<1024, 256, 0, stream>>>(x, Wbh, Wbl, bias, em);
  crf_serial_kernel<<<128, 320, 0, stream>>>(em, startv, endv, trans, labels, maskb,
                                             vhist, llp, lenp, lastp, midp);
  crf_bp_kernel<<<1024, 256, 0, stream>>>(vhist, em, trans, lenp, midp, bpbuf);
  crf_back_kernel<<<128, 64, 0, stream>>>(bpbuf, lenp, lastp, midp, out + 1);
  ll_reduce_kernel<<<1, 64, 0, stream>>>(llp, out);
}

// Round 17
// 187.287 us; speedup vs baseline: 1.3974x; 1.0870x over previous
//
#include <hip/hip_runtime.h>

#define Bq 128
#define Sq 512
#define Cq 37
#define Dq 768

typedef __attribute__((ext_vector_type(2))) float f32x2;
typedef __attribute__((ext_vector_type(4))) float f32x4;
typedef __attribute__((ext_vector_type(8))) short bf16x8;

static __device__ __forceinline__ f32x2 pk_fma(f32x2 a, f32x2 b, f32x2 c) {
  f32x2 d; asm("v_pk_fma_f32 %0, %1, %2, %3" : "=v"(d) : "v"(a), "v"(b), "v"(c));
  return d;
}
static __device__ __forceinline__ f32x2 pk_add(f32x2 a, f32x2 b) {
  f32x2 d; asm("v_pk_add_f32 %0, %1, %2" : "=v"(d) : "v"(a), "v"(b));
  return d;
}
static __device__ __forceinline__ float bcast(float v, int p) {
  return __int_as_float(__builtin_amdgcn_ds_bpermute(p << 2, __float_as_int(v)));
}

#define REP18(X) X(0)X(1)X(2)X(3)X(4)X(5)X(6)X(7)X(8)X(9)X(10)X(11)X(12)X(13) \
  X(14)X(15)X(16)X(17)
#define REP37(X) X(0)X(1)X(2)X(3)X(4)X(5)X(6)X(7)X(8)X(9)X(10)X(11)X(12)X(13) \
  X(14)X(15)X(16)X(17)X(18)X(19)X(20)X(21)X(22)X(23)X(24)X(25)X(26)X(27)X(28) \
  X(29)X(30)X(31)X(32)X(33)X(34)X(35)X(36)

// ---------------- Kernel 0: pre-split W into bf16 hi/lo B-fragments ----------------
__global__ __launch_bounds__(256) void prep_kernel(
    const float* __restrict__ W, unsigned short* __restrict__ Wbh,
    unsigned short* __restrict__ Wbl)
{
  int i = blockIdx.x * 256 + threadIdx.x;
  if (i >= 24 * 3 * 64 * 8) return;
  int ks = i / 1536, rem = i % 1536;
  int nt = rem / 512, rem2 = rem % 512;
  int lane = rem2 >> 3, j = rem2 & 7;
  int k = ks * 32 + (lane >> 4) * 8 + j;
  int c = nt * 16 + (lane & 15);
  float w = (c < Cq) ? W[(size_t)k * Cq + c] : 0.f;
  unsigned u = __float_as_uint(w);
  unsigned short h = (unsigned short)(u >> 16);
  float hr = __uint_as_float((unsigned)h << 16);
  float r = w - hr;
  Wbh[i] = h;
  Wbl[i] = (unsigned short)(__float_as_uint(r) >> 16);
}

// ---------------- Kernel 1: emissions via MFMA (R14, unchanged) ----------------
__global__ __launch_bounds__(256) void emis_kernel(
    const float* __restrict__ x, const unsigned short* __restrict__ Wbh,
    const unsigned short* __restrict__ Wbl, const float* __restrict__ bias,
    float* __restrict__ em)
{
  int tid = threadIdx.x, lane = tid & 63;
  int wv = tid >> 6;
  int tokBase = blockIdx.x * 64 + wv * 16;
  int row = lane & 15, kg = lane >> 4;
  const float* xr = x + (size_t)(tokBase + row) * Dq + kg * 8;
  const bf16x8* Bh = (const bf16x8*)Wbh;
  const bf16x8* Bl = (const bf16x8*)Wbl;
  f32x4 acc0 = {0.f, 0.f, 0.f, 0.f};
  f32x4 acc1 = {0.f, 0.f, 0.f, 0.f};
  f32x4 acc2 = {0.f, 0.f, 0.f, 0.f};

  float4 c0 = *(const float4*)(xr);
  float4 c1 = *(const float4*)(xr + 4);
  for (int ks = 0; ks < 24; ++ks) {
    float4 n0, n1;
    if (ks < 23) {
      n0 = *(const float4*)(xr + (ks + 1) * 32);
      n1 = *(const float4*)(xr + (ks + 1) * 32 + 4);
    }
    bf16x8 ah, al;
#define SPLIT(J, V) { unsigned u = __float_as_uint(V); \
    unsigned short h = (unsigned short)(u >> 16); \
    float hr = __uint_as_float((unsigned)h << 16); \
    float rr = (V) - hr; \
    ah[J] = (short)h; al[J] = (short)(__float_as_uint(rr) >> 16); }
    SPLIT(0, c0.x) SPLIT(1, c0.y) SPLIT(2, c0.z) SPLIT(3, c0.w)
    SPLIT(4, c1.x) SPLIT(5, c1.y) SPLIT(6, c1.z) SPLIT(7, c1.w)
#undef SPLIT
    int fi = (ks * 3) * 64 + lane;
    bf16x8 bh0 = Bh[fi], bh1 = Bh[fi + 64], bh2 = Bh[fi + 128];
    bf16x8 bl0 = Bl[fi], bl1 = Bl[fi + 64], bl2 = Bl[fi + 128];
    acc0 = __builtin_amdgcn_mfma_f32_16x16x32_bf16(al, bh0, acc0, 0, 0, 0);
    acc1 = __builtin_amdgcn_mfma_f32_16x16x32_bf16(al, bh1, acc1, 0, 0, 0);
    acc2 = __builtin_amdgcn_mfma_f32_16x16x32_bf16(al, bh2, acc2, 0, 0, 0);
    acc0 = __builtin_amdgcn_mfma_f32_16x16x32_bf16(ah, bl0, acc0, 0, 0, 0);
    acc1 = __builtin_amdgcn_mfma_f32_16x16x32_bf16(ah, bl1, acc1, 0, 0, 0);
    acc2 = __builtin_amdgcn_mfma_f32_16x16x32_bf16(ah, bl2, acc2, 0, 0, 0);
    acc0 = __builtin_amdgcn_mfma_f32_16x16x32_bf16(ah, bh0, acc0, 0, 0, 0);
    acc1 = __builtin_amdgcn_mfma_f32_16x16x32_bf16(ah, bh1, acc1, 0, 0, 0);
    acc2 = __builtin_amdgcn_mfma_f32_16x16x32_bf16(ah, bh2, acc2, 0, 0, 0);
    c0 = n0; c1 = n1;
  }
  int colc = lane & 15;
#pragma unroll
  for (int r = 0; r < 4; ++r) {
    size_t tok = (size_t)tokBase + kg * 4 + r;
    em[tok * Cq + colc]      = acc0[r] + bias[colc];
    em[tok * Cq + 16 + colc] = acc1[r] + bias[16 + colc];
    if (colc < 5)
      em[tok * Cq + 32 + colc] = acc2[r] + bias[32 + colc];
  }
}

// ---------------- Kernel 2: MEGA CRF — chains + bp/fp + backtrack in one block ----
// Phase 1 (5 waves): alpha fwd | beta bwd | vit fwd (v->vh) | vit bwd (u+em->vh)
//                    | gold. vh kept in LDS (512x40 floats).
// Phase 2: wave0 merge (logZ, mid tag); waves1-2 bp rows (t<=m) and waves3-4
//          fp rows (s>m) from vh via uniform b128 broadcasts -> bytes into the
//          dead semm space. Phase 3: wave0 register-gather backtrack -> tags.
__global__ __launch_bounds__(320) void crf_mega_kernel(
    const float* __restrict__ em, const float* __restrict__ startv,
    const float* __restrict__ endv, const float* __restrict__ trans,
    const int* __restrict__ labels, const unsigned char* __restrict__ maskb,
    float* __restrict__ llp, float* __restrict__ outp)
{
  __shared__ float semm[(Sq + 4) * Cq];            // 76,368 B; bpl overlay later
  __shared__ float vh[Sq * 40];                    // 81,920 B
  __shared__ __align__(16) float sxA[64];
  __shared__ __align__(16) float sxB[64];
  __shared__ __align__(16) float sxC[64];
  __shared__ __align__(16) float sxD[64];
  __shared__ float mrgA[64], mrgB[64], mrgV[64], mrgU[64];
  __shared__ float s_score;
  __shared__ int s_cstar;
  int b = blockIdx.x;
  int tid = threadIdx.x, wid = tid >> 6, lane = tid & 63;
  int cl = lane < Cq ? lane : Cq - 1;

  int esz4 = (maskb[1] == 0) ? 1 : 0;
  int len = 0;
#pragma unroll
  for (int k = 0; k < 8; ++k) {
    size_t t = (size_t)lane + (size_t)k * 64;
    unsigned char mb = esz4 ? maskb[((size_t)b * Sq + t) * 4] : maskb[(size_t)b * Sq + t];
    len += (mb != 0);
  }
#pragma unroll
  for (int off = 32; off; off >>= 1) len += __shfl_xor(len, off);
  int m = len >> 1;

  const float4* src4 = (const float4*)(em + (size_t)b * Sq * Cq);
  float4* dst4 = (float4*)semm;
  for (int i = tid; i < (Sq * Cq) / 4; i += 320) dst4[i] = src4[i];
  if (tid < 4 * Cq) semm[Sq * Cq + tid] = 0.f;
  __syncthreads();

  const float L2E = 1.4426950408889634f, LN2 = 0.6931471805599453f;

  if (wid == 0) {
    // ---- alpha forward, exp domain, t = 1..m ----
    f32x2 E2[18];
#pragma unroll
    for (int i = 0; i < 18; ++i) {
      E2[i][0] = exp2f(trans[(2 * i) * Cq + cl] * L2E);
      E2[i][1] = exp2f(trans[(2 * i + 1) * Cq + cl] * L2E);
    }
    float E36 = exp2f(trans[36 * Cq + cl] * L2E);
    const float4* se4 = (const float4*)sxA;
    float a0 = (lane < Cq) ? (startv[cl] + semm[cl]) : -3.0e38f;
    float K0 = bcast(a0, 0);
    float ez = (lane < Cq) ? exp2f((a0 - K0) * L2E) : 0.f;
    int eacc = 0;
    float wA = exp2f(semm[1 * Cq + cl] * L2E), wB = exp2f(semm[2 * Cq + cl] * L2E);
    float wC = exp2f(semm[3 * Cq + cl] * L2E), wD = exp2f(semm[4 * Cq + cl] * L2E);
    for (int t = 1; t <= m; ++t) {
      sxA[lane] = ez;
      int tn = (t + 4 <= m) ? t + 4 : m;
      float raw = semm[tn * Cq + cl];
      float4 gv[10];
#pragma unroll
      for (int q = 0; q < 10; ++q) gv[q] = se4[q];
      int e0 = ((__float_as_int(gv[0].x) >> 23) & 255) - 127;
      float scale = __int_as_float((127 - e0) << 23);
      f32x2 sa = {0.f, 0.f}, sb2 = {0.f, 0.f};
#define FPK(i) { f32x2 g; \
      g[0] = ((i) & 1) ? gv[(i) >> 1].z : gv[(i) >> 1].x; \
      g[1] = ((i) & 1) ? gv[(i) >> 1].w : gv[(i) >> 1].y; \
      if ((i) & 1) sb2 = pk_fma(g, E2[i], sb2); else sa = pk_fma(g, E2[i], sa); }
      REP18(FPK)
#undef FPK
      float dot = ((sa[0] + sb2[0]) + (sa[1] + sb2[1])) + gv[9].x * E36;
      float wcur = wA; wA = wB; wB = wC; wC = wD;
      ez = dot * (wcur * scale);
      eacc += e0;
      wD = exp2f(raw * L2E);
    }
    mrgA[lane] = (lane < Cq) ? LN2 * (log2f(ez) + (float)eacc) + K0 : -3.0e38f;
  } else if (wid == 1) {
    // ---- beta backward, exp domain, t = len-2..m (row-dot) ----
    f32x2 E2[18];
#pragma unroll
    for (int i = 0; i < 18; ++i) {
      E2[i][0] = exp2f(trans[cl * Cq + 2 * i] * L2E);
      E2[i][1] = exp2f(trans[cl * Cq + 2 * i + 1] * L2E);
    }
    float E36 = exp2f(trans[cl * Cq + 36] * L2E);
    const float4* se4 = (const float4*)sxB;
    float b0v = (lane < Cq) ? endv[cl] : -3.0e38f;
    float KB = bcast(b0v, 0);
    float bz = (lane < Cq) ? exp2f((b0v - KB) * L2E) : 0.f;
    int eacc = 0;
    float wA = exp2f(semm[(len - 1) * Cq + cl] * L2E);
    float wB = exp2f(semm[(len - 2) * Cq + cl] * L2E);
    float wC = exp2f(semm[(len - 3) * Cq + cl] * L2E);
    float wD = exp2f(semm[(len - 4) * Cq + cl] * L2E);
    for (int t = len - 2; t >= m; --t) {
      float wcur = wA; wA = wB; wB = wC; wC = wD;
      float s = bz * wcur;
      sxB[lane] = s;
      int tn = (t - 3 > 0) ? t - 3 : 0;
      float raw = semm[tn * Cq + cl];
      float4 gv[10];
#pragma unroll
      for (int q = 0; q < 10; ++q) gv[q] = se4[q];
      int e0 = ((__float_as_int(gv[0].x) >> 23) & 255) - 127;
      float scale = __int_as_float((127 - e0) << 23);
      f32x2 sa = {0.f, 0.f}, sb2 = {0.f, 0.f};
#define FPK(i) { f32x2 g; \
      g[0] = ((i) & 1) ? gv[(i) >> 1].z : gv[(i) >> 1].x; \
      g[1] = ((i) & 1) ? gv[(i) >> 1].w : gv[(i) >> 1].y; \
      if ((i) & 1) sb2 = pk_fma(g, E2[i], sb2); else sa = pk_fma(g, E2[i], sa); }
      REP18(FPK)
#undef FPK
      float dot = ((sa[0] + sb2[0]) + (sa[1] + sb2[1])) + gv[9].x * E36;
      bz = dot * scale;
      eacc += e0;
      wD = exp2f(raw * L2E);
    }
    mrgB[lane] = (lane < Cq) ? LN2 * (log2f(bz) + (float)eacc) + KB : -3.0e38f;
  } else if (wid == 2) {
    // ---- viterbi forward, t = 1..m; v -> vh[t] ----
    f32x2 T2[18];
#pragma unroll
    for (int i = 0; i < 18; ++i) {
      T2[i][0] = trans[(2 * i) * Cq + cl];
      T2[i][1] = trans[(2 * i + 1) * Cq + cl];
    }
    float T36 = trans[36 * Cq + cl];
    const float4* sv4 = (const float4*)sxC;
    float v = (lane < Cq) ? (startv[cl] + semm[cl]) : -3.0e38f;
    vh[0 * 40 + lane] = (lane < Cq) ? v : -3.0e38f;
    float emA = semm[1 * Cq + cl], emB = semm[2 * Cq + cl];
    float emC = semm[3 * Cq + cl], emD = semm[4 * Cq + cl];
    for (int t = 1; t <= m; ++t) {
      sxC[lane] = v;
      int tn = (t + 4 <= m) ? t + 4 : m;
      float raw = semm[tn * Cq + cl];
      float4 gv[10];
#pragma unroll
      for (int q = 0; q < 10; ++q) gv[q] = sv4[q];
      float m0 = -3.0e38f, m1 = -3.0e38f, m2 = -3.0e38f, m3 = -3.0e38f;
#define VPK(i) { f32x2 g; \
      g[0] = ((i) & 1) ? gv[(i) >> 1].z : gv[(i) >> 1].x; \
      g[1] = ((i) & 1) ? gv[(i) >> 1].w : gv[(i) >> 1].y; \
      f32x2 c = pk_add(g, T2[i]); \
      if (((i) & 3) == 0) m0 = fmaxf(fmaxf(m0, c[0]), c[1]); \
      else if (((i) & 3) == 1) m1 = fmaxf(fmaxf(m1, c[0]), c[1]); \
      else if (((i) & 3) == 2) m2 = fmaxf(fmaxf(m2, c[0]), c[1]); \
      else m3 = fmaxf(fmaxf(m3, c[0]), c[1]); }
      REP18(VPK)
#undef VPK
      float c36 = gv[9].x + T36;
      float best = fmaxf(fmaxf(fmaxf(m0, m1), fmaxf(m2, m3)), c36);
      float emc = emA; emA = emB; emB = emC; emC = emD;
      v = (lane < Cq) ? best + emc : -3.0e38f;
      vh[t * 40 + lane] = v;                // lanes>=37 write pad (harmless)
      emD = raw;
    }
    mrgV[lane] = v;
  } else if (wid == 3) {
    // ---- viterbi backward u; vh[t+1] = u[t+1]+em[t+1] (the exchanged value) ----
    f32x2 T2[18];
#pragma unroll
    for (int i = 0; i < 18; ++i) {
      T2[i][0] = trans[cl * Cq + 2 * i];
      T2[i][1] = trans[cl * Cq + 2 * i + 1];
    }
    float T36 = trans[cl * Cq + 36];
    const float4* sv4 = (const float4*)sxD;
    float u = (lane < Cq) ? endv[cl] : -3.0e38f;
    float emA = semm[(len - 1) * Cq + cl], emB = semm[(len - 2) * Cq + cl];
    float emC = semm[(len - 3) * Cq + cl], emD = semm[(len - 4) * Cq + cl];
    for (int t = len - 2; t >= m; --t) {
      float emc = emA; emA = emB; emB = emC; emC = emD;
      float s = u + emc;
      sxD[lane] = s;
      vh[(t + 1) * 40 + lane] = (lane < Cq) ? s : -3.0e38f;
      int tn = (t - 3 > 0) ? t - 3 : 0;
      float raw = semm[tn * Cq + cl];
      float4 gv[10];
#pragma unroll
      for (int q = 0; q < 10; ++q) gv[q] = sv4[q];
      float m0 = -3.0e38f, m1 = -3.0e38f, m2 = -3.0e38f, m3 = -3.0e38f;
#define VPK(i) { f32x2 g; \
      g[0] = ((i) & 1) ? gv[(i) >> 1].z : gv[(i) >> 1].x; \
      g[1] = ((i) & 1) ? gv[(i) >> 1].w : gv[(i) >> 1].y; \
      f32x2 c = pk_add(g, T2[i]); \
      if (((i) & 3) == 0) m0 = fmaxf(fmaxf(m0, c[0]), c[1]); \
      else if (((i) & 3) == 1) m1 = fmaxf(fmaxf(m1, c[0]), c[1]); \
      else if (((i) & 3) == 2) m2 = fmaxf(fmaxf(m2, c[0]), c[1]); \
      else m3 = fmaxf(fmaxf(m3, c[0]), c[1]); }
      REP18(VPK)
#undef VPK
      float c36 = gv[9].x + T36;
      float best = fmaxf(fmaxf(fmaxf(m0, m1), fmaxf(m2, m3)), c36);
      u = (lane < Cq) ? best : -3.0e38f;
      emD = raw;
    }
    mrgU[lane] = u;
  } else {
    // ---- gold path score ----
    const int* lab = labels + (size_t)b * Sq;
    float sc = 0.f;
#pragma unroll
    for (int k = 0; k < 8; ++k) {
      int t = 1 + lane + k * 64;
      if (t < len) {
        int lp = lab[t - 1], lt = lab[t];
        sc += trans[lp * Cq + lt] + semm[t * Cq + lt];
      }
    }
#pragma unroll
    for (int off = 32; off; off >>= 1) sc += __shfl_xor(sc, off);
    if (lane == 0) {
      int l0 = lab[0], lf = lab[len - 1];
      s_score = sc + startv[l0] + semm[l0] + endv[lf];
    }
  }
  __syncthreads();

  // ======== phase 2: merge (wave0) + bp/fp recompute (waves 1-4) ========
  unsigned char* bpl = (unsigned char*)semm;       // semm is dead now
  if (wid == 0) {
    float xv = (lane < Cq) ? mrgA[lane] + mrgB[lane] : -3.0e38f;
    float mm = xv;
#pragma unroll
    for (int off = 32; off; off >>= 1) mm = fmaxf(mm, __shfl_xor(mm, off));
    float es = exp2f((xv - mm) * L2E);
#pragma unroll
    for (int off = 32; off; off >>= 1) es += __shfl_xor(es, off);
    float logZ = mm + log2f(es) * LN2;
    float pv = (lane < Cq) ? mrgV[lane] + mrgU[lane] : -3.0e38f;
    int idx = (lane < Cq) ? lane : 1000;
#pragma unroll
    for (int off = 32; off; off >>= 1) {
      float po = __shfl_xor(pv, off); int io = __shfl_xor(idx, off);
      if (po > pv || (po == pv && io < idx)) { pv = po; idx = io; }
    }
    if (lane == 0) { llp[b] = s_score - logZ; s_cstar = idx; }
  } else if (wid <= 2) {
    // bp rows t = 1..m: bp[t][c] = argmax_p(vh[t-1][p] + trans[p][c])
#define DECLT(i) float T##i = trans[(i) * Cq + cl];
    REP37(DECLT)
#undef DECLT
    for (int t = wid; t <= m; t += 2) {            // wid 1,2 -> offsets 1,2
      const float4* vr4 = (const float4*)&vh[(t - 1) * 40];
      float4 gv[10];
#pragma unroll
      for (int q = 0; q < 10; ++q) gv[q] = vr4[q]; // uniform addr broadcast
      float br[40]; float4* br4 = (float4*)br;
#pragma unroll
      for (int q = 0; q < 10; ++q) br4[q] = gv[q];
      float best = -3.0e38f; int bi = 0;
#define BARG(i) { float cnd = br[i] + T##i; if (cnd > best) { best = cnd; bi = (i); } }
      REP37(BARG)
#undef BARG
      if (lane < Cq) bpl[cl * 520 + t] = (unsigned char)bi;
    }
  } else {
    // fp rows s = m+1..len-1: fp[s][c] = argmax_n(vh[s][n] + trans[c][n])
#define DECLR(i) float R##i = trans[cl * Cq + (i)];
    REP37(DECLR)
#undef DECLR
    for (int s = m + 1 + (wid - 3); s < len; s += 2) {  // wid 3,4 -> off 0,1
      const float4* vr4 = (const float4*)&vh[s * 40];
      float4 gv[10];
#pragma unroll
      for (int q = 0; q < 10; ++q) gv[q] = vr4[q];
      float br[40]; float4* br4 = (float4*)br;
#pragma unroll
      for (int q = 0; q < 10; ++q) br4[q] = gv[q];
      float best = -3.0e38f; int bi = 0;
#define BARG(i) { float cnd = br[i] + R##i; if (cnd > best) { best = cnd; bi = (i); } }
      REP37(BARG)
#undef BARG
      if (lane < Cq) bpl[cl * 520 + s] = (unsigned char)bi;
    }
  }
  __syncthreads();

  // ======== phase 3: backtrack (wave0) ========
  if (wid == 0) {
    int cstar = __builtin_amdgcn_readfirstlane(s_cstar);
    int lenv = __builtin_amdgcn_readfirstlane(len);
    int mv = __builtin_amdgcn_readfirstlane(m);
    int rowc = lane < Cq ? lane : Cq - 1;
    const unsigned* rw = (const unsigned*)(bpl + rowc * 520);
    unsigned r[128];
#pragma unroll
    for (int k = 0; k < 128; ++k) r[k] = rw[k];    // lane c: bp[c][4k..4k+3]
    unsigned vt[8];
#pragma unroll
    for (int j = 0; j < 8; ++j) vt[j] = 0u;
#pragma unroll
    for (int j = 0; j < 8; ++j)
      vt[j] = (lane == (mv & 63) && (mv >> 6) == j) ? (unsigned)cstar : vt[j];
    { // forward walk: t = m+1..len-1 via fp rows
      int tag = cstar;
#pragma unroll
      for (int t = 1; t <= 510; ++t) {
        int word = __builtin_amdgcn_readlane((int)r[t >> 2], tag);
        int nt = (word >> ((t & 3) * 8)) & 0xff;
        bool live = (t > mv) && (t < lenv);
        tag = live ? nt : tag;
        vt[t >> 6] = (lane == (t & 63) && live) ? (unsigned)tag : vt[t >> 6];
      }
    }
    { // backward walk: t = m-1..0 via bp rows
      int tag = cstar;
#pragma unroll
      for (int t = 510; t >= 0; --t) {
        int word = __builtin_amdgcn_readlane((int)r[(t + 1) >> 2], tag);
        int nt = (word >> (((t + 1) & 3) * 8)) & 0xff;
        bool live = (t + 1 <= mv);
        tag = live ? nt : tag;
        vt[t >> 6] = (lane == (t & 63) && live) ? (unsigned)tag : vt[t >> 6];
      }
    }
#pragma unroll
    for (int j = 0; j < 8; ++j) {
      int t = j * 64 + lane;
      float o = (t < lenv) ? (float)(int)vt[j] : 36.0f;
      outp[(size_t)b * Sq + t] = o;
    }
  }
}

// ---------------- Kernel 3: reduce ll partials ----------------
__global__ __launch_bounds__(64) void ll_reduce_kernel(
    const float* __restrict__ llp, float* __restrict__ outp)
{
  int lane = threadIdx.x;
  float s = llp[lane] + llp[lane + 64];
#pragma unroll
  for (int off = 32; off; off >>= 1) s += __shfl_xor(s, off);
  if (lane == 0) outp[0] = s;
}

extern "C" void kernel_launch(void* const* d_in, const int* in_sizes, int n_in,
                              void* d_out, int out_size, void* d_ws, size_t ws_size,
                              hipStream_t stream)
{
  const float* x      = (const float*)d_in[0];
  const float* W      = (const float*)d_in[1];
  const float* bias   = (const float*)d_in[2];
  const float* startv = (const float*)d_in[3];
  const float* endv   = (const float*)d_in[4];
  const float* trans  = (const float*)d_in[5];
  const int*   labels = (const int*)d_in[6];
  const unsigned char* maskb = (const unsigned char*)d_in[7];
  float* out = (float*)d_out;

  char* ws = (char*)d_ws;
  float* em            = (float*)(ws);                    // 9,699,328 B
  float* llp           = (float*)(ws + 9699328);          // 512 B
  unsigned short* Wbh  = (unsigned short*)(ws + 9699840); // 73,728 B
  unsigned short* Wbl  = (unsigned short*)(ws + 9773568); // 73,728 B

  prep_kernel<<<144, 256, 0, stream>>>(W, Wbh, Wbl);
  emis_kernel<<<1024, 256, 0, stream>>>(x, Wbh, Wbl, bias, em);
  crf_mega_kernel<<<128, 320, 0, stream>>>(em, startv, endv, trans, labels, maskb,
                                           llp, out + 1);
  ll_reduce_kernel<<<1, 64, 0, stream>>>(llp, out);
}